// Round 2
// baseline (605.247 us; speedup 1.0000x reference)
//
#include <hip/hip_runtime.h>

// SimAttn: out = softmax(1000*softmax(QK^T/sqrt(dk))) @ V, fp32 I/O.
// Two-pass flash, all-f16 MFMA:
//   pass 1: f16 QK^T -> row max m (raw-score units) and l8 = sum exp(s-8)
//           (fixed stabilizer 8 > any score; m cancels analytically)
//   pass 2: identical f16 QK^T (bitwise-equal scores), p' = exp(s-8),
//           w = exp(u'*(p' - pm)), u' = 1000/l8, pm = exp(m-8)  [w <= ~1]
//           PV via f16 MFMA on unnormalized w; divide by sum(w) at end.
// LDS = 40960 B -> 4 blocks/CU (was 57344 -> 2).

typedef __attribute__((ext_vector_type(4))) float f32x4;
typedef __attribute__((ext_vector_type(8))) _Float16 h16x8;
typedef __attribute__((ext_vector_type(4))) _Float16 h16x4;
typedef __attribute__((ext_vector_type(8))) short s16x8;
typedef __attribute__((ext_vector_type(4))) short s16x4;

#define NB 4
#define T_ 2048
#define D_ 1024
#define NH 8
#define DK 128
#define BQ 64
#define KB 64
#define NKC (T_ / KB)
#define SCALE 0.08838834764831845f  // 1/sqrt(128)
#define MOFF 8.0f                   // fixed stabilizer, > max possible score

__device__ __forceinline__ unsigned short h2u(_Float16 h) {
  return __builtin_bit_cast(unsigned short, h);
}

__global__ __launch_bounds__(256, 4) void simattn_f16(
    const float* __restrict__ Qg, const float* __restrict__ Kg,
    const float* __restrict__ Vg, float* __restrict__ Og) {
  // K row-major [key][d] f16, 16B XOR swizzle; V transposed [d][key]; w [q][key].
  __shared__ __align__(16) unsigned short kf[KB][DK];    // 16 KB
  __shared__ __align__(16) unsigned short vts[DK][KB];   // 16 KB
  __shared__ __align__(16) unsigned short wls[BQ][KB];   //  8 KB

  const int tid  = threadIdx.x;
  const int wid  = tid >> 6;
  const int lane = tid & 63;
  const int lr   = lane & 15;   // A-row / B-col / C-col within 16
  const int lg   = lane >> 4;   // k-slot group; C-row group

  const int blk  = blockIdx.x;
  const int qblk = blk & (T_ / BQ - 1);
  const int h    = (blk >> 5) & (NH - 1);
  const int b    = blk >> 8;

  const int q0 = qblk * BQ;
  const size_t bh = (size_t)b * (T_ * D_) + (size_t)h * DK;

  // ---- Q fragments (f16), kept in registers --------------------------------
  h16x8 qf[4];
  {
    const float* qp = Qg + bh + (size_t)(q0 + wid * 16 + lr) * D_;
#pragma unroll
    for (int s = 0; s < 4; ++s) {
      const int d0 = s * 32 + lg * 8;
      f32x4 x0 = *(const f32x4*)(qp + d0);
      f32x4 x1 = *(const f32x4*)(qp + d0 + 4);
#pragma unroll
      for (int i = 0; i < 8; ++i) {
        float x = (i < 4) ? x0[i] : x1[i - 4];
        qf[s][i] = (_Float16)x;
      }
    }
  }

  // ---- pass 1: row max (raw units) + l8 = sum exp(s*SCALE - 8) -------------
  float msc[4], l8[4];
#pragma unroll
  for (int r = 0; r < 4; ++r) { msc[r] = -3.0e38f; l8[r] = 0.f; }

  for (int kc = 0; kc < NKC; ++kc) {
    __syncthreads();
    {
      const float* kp = Kg + bh + (size_t)kc * KB * D_;
#pragma unroll
      for (int p = 0; p < 8; ++p) {
        const int j = tid + p * 256;
        const int row = j >> 5, c4 = j & 31;
        f32x4 v = *(const f32x4*)(kp + (size_t)row * D_ + c4 * 4);
        h16x4 hv;
#pragma unroll
        for (int i = 0; i < 4; ++i) hv[i] = (_Float16)v[i];
        const int e = (c4 * 4) ^ ((row & 7) << 3);
        *(s16x4*)&kf[row][e] = __builtin_bit_cast(s16x4, hv);
      }
    }
    __syncthreads();

    f32x4 sc[4];
#pragma unroll
    for (int nt = 0; nt < 4; ++nt) sc[nt] = (f32x4){0.f, 0.f, 0.f, 0.f};
#pragma unroll
    for (int s = 0; s < 4; ++s) {
#pragma unroll
      for (int nt = 0; nt < 4; ++nt) {
        const int kr = nt * 16 + lr;
        const int e = (s * 32 + lg * 8) ^ ((kr & 7) << 3);
        h16x8 bf = __builtin_bit_cast(h16x8, *(const s16x8*)&kf[kr][e]);
        sc[nt] = __builtin_amdgcn_mfma_f32_16x16x32_f16(qf[s], bf, sc[nt], 0, 0, 0);
      }
    }
#pragma unroll
    for (int r = 0; r < 4; ++r) {
      const float s0 = sc[0][r], s1 = sc[1][r], s2 = sc[2][r], s3 = sc[3][r];
      msc[r] = fmaxf(msc[r], fmaxf(fmaxf(s0, s1), fmaxf(s2, s3)));
      const float e0 = __expf(fmaf(s0, SCALE, -MOFF));
      const float e1 = __expf(fmaf(s1, SCALE, -MOFF));
      const float e2 = __expf(fmaf(s2, SCALE, -MOFF));
      const float e3 = __expf(fmaf(s3, SCALE, -MOFF));
      l8[r] += (e0 + e1) + (e2 + e3);
    }
  }

  // merge stats across the 16 column-lanes (lane bits 0..3)
  float u_[4], mcu[4];
#pragma unroll
  for (int r = 0; r < 4; ++r) {
    float m = msc[r], l = l8[r];
#pragma unroll
    for (int off = 1; off < 16; off <<= 1) {
      m = fmaxf(m, __shfl_xor(m, off));
      l += __shfl_xor(l, off);
    }
    const float pm = __expf(fmaf(m, SCALE, -MOFF));  // == max_k p'_k (bitwise)
    u_[r] = 1000.0f / l;
    mcu[r] = -u_[r] * pm;
  }

  // ---- pass 2: f16 scores -> weights -> PV ---------------------------------
  f32x4 y[8];
#pragma unroll
  for (int dt = 0; dt < 8; ++dt) y[dt] = (f32x4){0.f, 0.f, 0.f, 0.f};
  float W_run[4] = {0.f, 0.f, 0.f, 0.f};

  for (int kc = 0; kc < NKC; ++kc) {
    __syncthreads();
    {
      const float* kp = Kg + bh + (size_t)kc * KB * D_;
      const float* vp = Vg + bh + (size_t)kc * KB * D_;
#pragma unroll
      for (int p = 0; p < 8; ++p) {
        const int j = tid + p * 256;
        const int row = j >> 5, c4 = j & 31;
        f32x4 v = *(const f32x4*)(kp + (size_t)row * D_ + c4 * 4);
        h16x4 hv;
#pragma unroll
        for (int i = 0; i < 4; ++i) hv[i] = (_Float16)v[i];
        const int e = (c4 * 4) ^ ((row & 7) << 3);
        *(s16x4*)&kf[row][e] = __builtin_bit_cast(s16x4, hv);
        f32x4 vv = *(const f32x4*)(vp + (size_t)row * D_ + c4 * 4);
#pragma unroll
        for (int i = 0; i < 4; ++i) {
          const int d = c4 * 4 + i;
          vts[d][row ^ ((d & 7) << 3)] = h2u((_Float16)vv[i]);
        }
      }
    }
    __syncthreads();

    f32x4 sc[4];
#pragma unroll
    for (int nt = 0; nt < 4; ++nt) sc[nt] = (f32x4){0.f, 0.f, 0.f, 0.f};
#pragma unroll
    for (int s = 0; s < 4; ++s) {
#pragma unroll
      for (int nt = 0; nt < 4; ++nt) {
        const int kr = nt * 16 + lr;
        const int e = (s * 32 + lg * 8) ^ ((kr & 7) << 3);
        h16x8 bf = __builtin_bit_cast(h16x8, *(const s16x8*)&kf[kr][e]);
        sc[nt] = __builtin_amdgcn_mfma_f32_16x16x32_f16(qf[s], bf, sc[nt], 0, 0, 0);
      }
    }

    // weights: p' = exp(s-8); w = exp(u'*(p'-pm)) <= ~1, f16-safe
#pragma unroll
    for (int nt = 0; nt < 4; ++nt) {
#pragma unroll
      for (int r = 0; r < 4; ++r) {
        const float pp = __expf(fmaf(sc[nt][r], SCALE, -MOFF));
        const float w  = __expf(fmaf(pp, u_[r], mcu[r]));
        W_run[r] += w;
        const int qr = lg * 4 + r;
        wls[wid * 16 + qr][(nt * 16 + lr) ^ ((qr & 7) << 3)] = h2u((_Float16)w);
      }
    }

    // PV: A = w-tile rows (same-wave LDS dep), B = transposed V
#pragma unroll
    for (int ks = 0; ks < 2; ++ks) {
      const int e = (ks * 32 + lg * 8) ^ ((lr & 7) << 3);
      h16x8 af = __builtin_bit_cast(h16x8, *(const s16x8*)&wls[wid * 16 + lr][e]);
#pragma unroll
      for (int dt = 0; dt < 8; ++dt) {
        const int d = dt * 16 + lr;
        const int ev = (ks * 32 + lg * 8) ^ ((d & 7) << 3);
        h16x8 vf = __builtin_bit_cast(h16x8, *(const s16x8*)&vts[d][ev]);
        y[dt] = __builtin_amdgcn_mfma_f32_16x16x32_f16(af, vf, y[dt], 0, 0, 0);
      }
    }
  }

  // normalize by sum(w) (reduced over the 16 column-lanes) and store
#pragma unroll
  for (int r = 0; r < 4; ++r) {
    float Wv = W_run[r];
#pragma unroll
    for (int off = 1; off < 16; off <<= 1) Wv += __shfl_xor(Wv, off);
    W_run[r] = 1.0f / Wv;
  }

  float* op = Og + bh + (size_t)(q0 + wid * 16) * D_;
#pragma unroll
  for (int dt = 0; dt < 8; ++dt) {
#pragma unroll
    for (int r = 0; r < 4; ++r) {
      op[(size_t)(lg * 4 + r) * D_ + dt * 16 + lr] = y[dt][r] * W_run[r];
    }
  }
}

extern "C" void kernel_launch(void* const* d_in, const int* in_sizes, int n_in,
                              void* d_out, int out_size, void* d_ws, size_t ws_size,
                              hipStream_t stream) {
  (void)in_sizes; (void)n_in; (void)d_ws; (void)ws_size; (void)out_size;
  const float* Q = (const float*)d_in[0];
  const float* K = (const float*)d_in[1];
  const float* V = (const float*)d_in[2];
  float* O = (float*)d_out;
  dim3 grid(NB * NH * (T_ / BQ));  // 1024 workgroups, 4 waves each
  simattn_f16<<<grid, 256, 0, stream>>>(Q, K, V, O);
}

// Round 3
// 252.539 us; speedup vs baseline: 2.3966x; 2.3966x over previous
//
#include <hip/hip_runtime.h>

// SimAttn: out = softmax(1000*softmax(QK^T/sqrt(dk))) @ V, fp32 I/O.
// Two-pass flash, all-f16 MFMA, swapped QK^T (S^T = K·Q) so each lane owns one
// q-row with adjacent-k score pairs:
//   pass 1: f16 QK^T -> row max m, l8 = sum exp(s*SCALE-8)  (fixed stabilizer)
//   pass 2: bitwise-identical scores, p=exp(s*SCALE-8), w=exp(u*(p-pm)),
//           u=1000/l8, pm=exp(m*SCALE-8) (exact row max of p) -> w<=~1.
//           w packed (cvt_pkrtz) -> LDS dwords -> A-frags; PV f16 MFMA;
//           normalize by sum(w) at the end.
// LDS layouts are bank-spread: K row-major + 8-elem XOR swizzle (vector 8B
// stores); V^T staged d-major with coalesced global gathers + b128 stores into
// 16B slots slot=(k/8)^(d&7); w tile dword-packed with slot XOR.

typedef __attribute__((ext_vector_type(4))) float f32x4;
typedef __attribute__((ext_vector_type(8))) _Float16 h16x8;
typedef __attribute__((ext_vector_type(4))) _Float16 h16x4;
typedef __attribute__((ext_vector_type(8))) short s16x8;
typedef __attribute__((ext_vector_type(4))) short s16x4;
typedef __attribute__((ext_vector_type(2))) unsigned int u32x2;
typedef __attribute__((ext_vector_type(4))) unsigned int u32x4;

#define NB 4
#define T_ 2048
#define D_ 1024
#define NH 8
#define DK 128
#define BQ 64
#define KB 64
#define NKC (T_ / KB)
#define SCALE 0.08838834764831845f  // 1/sqrt(128)
#define MOFF 8.0f                   // fixed stabilizer, > max possible score

__device__ __forceinline__ unsigned int pk2(float a, float b) {
  return __builtin_bit_cast(unsigned int, __builtin_amdgcn_cvt_pkrtz(a, b));
}
#define H8(p) __builtin_bit_cast(h16x8, *(const s16x8*)(p))

__global__ __launch_bounds__(256, 4) void simattn_v3(
    const float* __restrict__ Qg, const float* __restrict__ Kg,
    const float* __restrict__ Vg, float* __restrict__ Og) {
  __shared__ __align__(16) unsigned short kf[KB][DK];    // 16 KB
  __shared__ __align__(16) unsigned short vts[DK][KB];   // 16 KB (V^T, slotted)
  __shared__ __align__(16) unsigned int   wls[4][16][32];//  8 KB (w, dword-packed)

  const int tid  = threadIdx.x;
  const int wid  = tid >> 6;
  const int lane = tid & 63;
  const int lr   = lane & 15;   // q-row (B-col of swapped QK; A-row of PV)
  const int lg   = lane >> 4;   // k-slot group

  const int blk  = blockIdx.x;
  const int qblk = blk & (T_ / BQ - 1);
  const int h    = (blk >> 5) & (NH - 1);
  const int b    = blk >> 8;
  const int q0   = qblk * BQ;
  const size_t bh = (size_t)b * (T_ * D_) + (size_t)h * DK;

  // ---- Q fragments (f16, RNE), kept in registers ---------------------------
  h16x8 qf[4];
  {
    const float* qp = Qg + bh + (size_t)(q0 + wid * 16 + lr) * D_;
#pragma unroll
    for (int s = 0; s < 4; ++s) {
      const int d0 = s * 32 + lg * 8;
      f32x4 x0 = *(const f32x4*)(qp + d0);
      f32x4 x1 = *(const f32x4*)(qp + d0 + 4);
#pragma unroll
      for (int i = 0; i < 4; ++i) {
        qf[s][i]     = (_Float16)x0[i];
        qf[s][i + 4] = (_Float16)x1[i];
      }
    }
  }

  // K staging: row-major [key][d] f16, 8-element XOR swizzle, 8B stores.
  auto stageK = [&](int kc) {
    const float* kp = Kg + bh + (size_t)kc * KB * D_;
#pragma unroll
    for (int p = 0; p < 8; ++p) {
      const int j = tid + p * 256;
      const int row = j >> 5, c4 = j & 31;
      f32x4 v = *(const f32x4*)(kp + (size_t)row * D_ + c4 * 4);
      h16x4 hv;
#pragma unroll
      for (int i = 0; i < 4; ++i) hv[i] = (_Float16)v[i];  // RNE
      const int e = (c4 * 4) ^ ((row & 7) << 3);
      *(s16x4*)&kf[row][e] = __builtin_bit_cast(s16x4, hv);
    }
  };

  // Swapped QK^T: st[nt][r] = S[k = nt*16 + lg*4 + r][q = lr]
  auto qkT = [&](f32x4* st) {
#pragma unroll
    for (int nt = 0; nt < 4; ++nt) st[nt] = (f32x4){0.f, 0.f, 0.f, 0.f};
#pragma unroll
    for (int s = 0; s < 4; ++s) {
#pragma unroll
      for (int nt = 0; nt < 4; ++nt) {
        const int kr = nt * 16 + lr;
        const int e = (s * 32 + lg * 8) ^ ((kr & 7) << 3);
        st[nt] = __builtin_amdgcn_mfma_f32_16x16x32_f16(H8(&kf[kr][e]), qf[s],
                                                        st[nt], 0, 0, 0);
      }
    }
  };

  // ---- pass 1: per-q max (raw units) + l8 = sum exp(s*SCALE - 8) -----------
  float msc = -3.0e38f, l8 = 0.f;
  for (int kc = 0; kc < NKC; ++kc) {
    __syncthreads();
    stageK(kc);
    __syncthreads();
    f32x4 st[4];
    qkT(st);
#pragma unroll
    for (int nt = 0; nt < 4; ++nt) {
#pragma unroll
      for (int r = 0; r < 4; ++r) {
        const float s = st[nt][r];
        msc = fmaxf(msc, s);
        l8 += __expf(fmaf(s, SCALE, -MOFF));
      }
    }
  }
  // merge across the 4 lane-groups (this lane's q = lr)
  msc = fmaxf(msc, __shfl_xor(msc, 16));
  msc = fmaxf(msc, __shfl_xor(msc, 32));
  l8 += __shfl_xor(l8, 16);
  l8 += __shfl_xor(l8, 32);
  const float pm  = __expf(fmaf(msc, SCALE, -MOFF));  // exact max_k p_k
  const float u_  = 1000.0f / l8;
  const float mcu = -u_ * pm;

  // ---- pass 2: scores -> weights -> PV -------------------------------------
  f32x4 y[8];
#pragma unroll
  for (int dt = 0; dt < 8; ++dt) y[dt] = (f32x4){0.f, 0.f, 0.f, 0.f};
  float Wl = 0.f;
  const int dv  = tid & 127;  // V^T staging: this thread's d-row
  const int kg0 = tid >> 7;

  for (int kc = 0; kc < NKC; ++kc) {
    __syncthreads();
    stageK(kc);
    {
      // V^T staging: coalesced d-major gathers, one b128 store per task.
      const float* vp = Vg + bh + (size_t)kc * KB * D_ + dv;
#pragma unroll
      for (int i = 0; i < 4; ++i) {
        const int kg = kg0 + 2 * i;              // k-group of 8
        const float* vq = vp + (size_t)kg * 8 * D_;
        const float x0 = vq[0],      x1 = vq[D_],     x2 = vq[2 * D_], x3 = vq[3 * D_];
        const float x4 = vq[4 * D_], x5 = vq[5 * D_], x6 = vq[6 * D_], x7 = vq[7 * D_];
        u32x4 pv;
        pv[0] = pk2(x0, x1); pv[1] = pk2(x2, x3);
        pv[2] = pk2(x4, x5); pv[3] = pk2(x6, x7);
        *(u32x4*)&vts[dv][(kg ^ (dv & 7)) * 8] = pv;
      }
    }
    __syncthreads();

    f32x4 st[4];
    qkT(st);  // bitwise-identical to pass 1

    // weights for q = lr, k = nt*16 + lg*4 + r; pack adjacent-k pairs.
#pragma unroll
    for (int nt = 0; nt < 4; ++nt) {
      float w[4];
#pragma unroll
      for (int r = 0; r < 4; ++r) {
        const float pp = __expf(fmaf(st[nt][r], SCALE, -MOFF));
        w[r] = __expf(fmaf(pp, u_, mcu));
      }
      Wl += (w[0] + w[1]) + (w[2] + w[3]);
      u32x2 pk;
      pk[0] = pk2(w[0], w[1]);
      pk[1] = pk2(w[2], w[3]);
      *(u32x2*)&wls[wid][lr][(nt * 8 + lg * 2) ^ ((lr & 7) << 2)] = pk;
    }

    // PV: A = w rows (same-wave LDS round-trip), B = slotted V^T.
#pragma unroll
    for (int ks = 0; ks < 2; ++ks) {
      h16x8 af = H8((const unsigned short*)&wls[wid][lr]
                    [(ks * 16 + lg * 4) ^ ((lr & 7) << 2)]);
#pragma unroll
      for (int dt = 0; dt < 8; ++dt) {
        const int d = dt * 16 + lr;
        h16x8 vf = H8(&vts[d][((ks * 4 + lg) ^ (d & 7)) * 8]);
        y[dt] = __builtin_amdgcn_mfma_f32_16x16x32_f16(af, vf, y[dt], 0, 0, 0);
      }
    }
  }

  // ---- normalize and store -------------------------------------------------
  Wl += __shfl_xor(Wl, 16);
  Wl += __shfl_xor(Wl, 32);
  const float winv = 1.0f / Wl;  // valid for q = lr

  float* op = Og + bh + (size_t)(q0 + wid * 16) * D_;
#pragma unroll
  for (int r = 0; r < 4; ++r) {
    const float wv = __shfl(winv, lg * 4 + r);  // fetch W for q-row lg*4+r
#pragma unroll
    for (int dt = 0; dt < 8; ++dt) {
      op[(size_t)(lg * 4 + r) * D_ + dt * 16 + lr] = y[dt][r] * wv;
    }
  }
}

extern "C" void kernel_launch(void* const* d_in, const int* in_sizes, int n_in,
                              void* d_out, int out_size, void* d_ws, size_t ws_size,
                              hipStream_t stream) {
  (void)in_sizes; (void)n_in; (void)d_ws; (void)ws_size; (void)out_size;
  const float* Q = (const float*)d_in[0];
  const float* K = (const float*)d_in[1];
  const float* V = (const float*)d_in[2];
  float* O = (float*)d_out;
  dim3 grid(NB * NH * (T_ / BQ));  // 1024 workgroups, 4 waves each
  simattn_v3<<<grid, 256, 0, stream>>>(Q, K, V, O);
}